// Round 1
// baseline (374.205 us; speedup 1.0000x reference)
//
#include <hip/hip_runtime.h>
#include <cstdint>

#define B_   16
#define H_   128
#define W_   128
#define C_   64
#define HID_ 256

typedef __attribute__((ext_vector_type(8))) short short8v;   // 8 bf16 (4 VGPRs)
typedef __attribute__((ext_vector_type(4))) float f32x4;

typedef unsigned short ushort_t;

__device__ __forceinline__ ushort_t f2bf(float f) {
  uint32_t u = __builtin_bit_cast(uint32_t, f);
  u += 0x7fff + ((u >> 16) & 1);          // round-to-nearest-even
  return (ushort_t)(u >> 16);
}

// ---------------------------------------------------------------------------
// Phase 0: convert W1 [320x256] f32 and W2 [256x64] f32 into bf16 fragments
// pre-swizzled for mfma_f32_16x16x32_bf16 B-operand:
//   lane l of a fragment needs B[k0 + (l>>4)*8 + j][n0 + (l&15)], j=0..7
// stored so each lane's 8 bf16 are 16B contiguous, lanes contiguous.
// w1s index: ((ks*16 + n16)*64 + lane)*8 + j   (ks=0..9, n16=0..15)
// w2s index: ((ks*4  + n16)*64 + lane)*8 + j   (ks=0..7, n16=0..3)
// ---------------------------------------------------------------------------
__global__ void cvt_weights_kernel(const float* __restrict__ W1,
                                   const float* __restrict__ W2,
                                   ushort_t* __restrict__ w1s,
                                   ushort_t* __restrict__ w2s) {
  int t = blockIdx.x * 256 + threadIdx.x;
  if (t < 81920) {
    int j = t & 7, lane = (t >> 3) & 63, n16 = (t >> 9) & 15, ks = t >> 13;
    int k = ks * 32 + (lane >> 4) * 8 + j;
    int n = n16 * 16 + (lane & 15);
    w1s[t] = f2bf(W1[k * 256 + n]);
  } else if (t < 81920 + 16384) {
    int t2 = t - 81920;
    int j = t2 & 7, lane = (t2 >> 3) & 63, n16 = (t2 >> 9) & 3, ks = t2 >> 11;
    int k = ks * 32 + (lane >> 4) * 8 + j;
    int n = n16 * 16 + (lane & 15);
    w2s[t2] = f2bf(W2[k * 64 + n]);
  }
}

// ---------------------------------------------------------------------------
// Fused NCA kernel: one block = 8x8 pixel tile of one image, 256 threads.
// conv(4 dilations) -> feat[64][320] bf16 LDS -> GEMM1+bias+GELU ->
// h[64][256] bf16 LDS -> GEMM2+bias -> out = x + delta (fp32 residual)
// ---------------------------------------------------------------------------
__global__ void nca_fused_kernel(const float* __restrict__ x,
                                 const float* __restrict__ cw,
                                 const float* __restrict__ b1,
                                 const float* __restrict__ b2,
                                 const ushort_t* __restrict__ w1s,
                                 const ushort_t* __restrict__ w2s,
                                 float* __restrict__ out) {
  // feat rows padded 320 -> 328 (stride 656B = 164 dw == 4 mod 32 banks)
  __shared__ __align__(16) ushort_t feat[64 * 328];
  // h rows padded 256 -> 264 (stride 528B = 132 dw == 4 mod 32 banks)
  __shared__ __align__(16) ushort_t hbuf[64 * 264];

  const int tid   = threadIdx.x;
  const int tileX = blockIdx.x * 8;
  const int tileY = blockIdx.y * 8;
  const int batch = blockIdx.z;
  const float* xb = x + (size_t)batch * (H_ * W_ * C_);

  // ---- phase 1a: copy x tile into feat[:, 0:64] as bf16 ----
#pragma unroll
  for (int i = 0; i < 4; ++i) {
    int item = i * 256 + tid;          // 1024 items = 64 px * 16 quads
    int quad = item & 15;
    int p    = item >> 4;
    int py = p >> 3, px = p & 7;
    const float4 v =
        *(const float4*)&xb[((tileY + py) * W_ + (tileX + px)) * C_ + quad * 4];
    ushort4 pk;
    pk.x = f2bf(v.x); pk.y = f2bf(v.y); pk.z = f2bf(v.z); pk.w = f2bf(v.w);
    *(ushort4*)&feat[p * 328 + quad * 4] = pk;
  }

  // ---- phase 1b: 4 dilated depthwise 3x3 convs into feat[:, 64:320] ----
  for (int d = 0; d < 4; ++d) {
    const int dil = 1 << d;
#pragma unroll
    for (int i = 0; i < 4; ++i) {
      int item = i * 256 + tid;
      int quad = item & 15;
      int p    = item >> 4;
      int py = p >> 3, px = p & 7;
      int y0 = tileY + py, x0 = tileX + px;
      float a0 = 0.f, a1 = 0.f, a2 = 0.f, a3 = 0.f;
#pragma unroll
      for (int ky = 0; ky < 3; ++ky) {
        int yy = y0 + (ky - 1) * dil;
        if ((unsigned)yy >= (unsigned)H_) continue;
#pragma unroll
        for (int kx = 0; kx < 3; ++kx) {
          int xx = x0 + (kx - 1) * dil;
          if ((unsigned)xx >= (unsigned)W_) continue;
          const float4 xv = *(const float4*)&xb[(yy * W_ + xx) * C_ + quad * 4];
          const float4 wv =
              *(const float4*)&cw[(d * 9 + ky * 3 + kx) * C_ + quad * 4];
          a0 = fmaf(xv.x, wv.x, a0);
          a1 = fmaf(xv.y, wv.y, a1);
          a2 = fmaf(xv.z, wv.z, a2);
          a3 = fmaf(xv.w, wv.w, a3);
        }
      }
      ushort4 pk;
      pk.x = f2bf(a0); pk.y = f2bf(a1); pk.z = f2bf(a2); pk.w = f2bf(a3);
      *(ushort4*)&feat[p * 328 + 64 + d * 64 + quad * 4] = pk;
    }
  }
  __syncthreads();

  // ---- phase 2: GEMM1  [64 x 320] @ [320 x 256] ----
  const int lane = tid & 63;
  const int wv   = tid >> 6;       // wave 0..3
  const int lr   = lane & 15;      // row (A) / col (B,C)
  const int lg   = lane >> 4;      // lanegroup 0..3
  const int n0   = wv * 64;        // this wave's N range in GEMM1

  f32x4 acc[4][4];
#pragma unroll
  for (int mi = 0; mi < 4; ++mi)
#pragma unroll
    for (int ni = 0; ni < 4; ++ni) acc[mi][ni] = 0;

  const short8v* w1v = (const short8v*)w1s;
  for (int ks = 0; ks < 10; ++ks) {
    short8v af[4], bf[4];
#pragma unroll
    for (int mi = 0; mi < 4; ++mi)
      af[mi] = *(const short8v*)&feat[(mi * 16 + lr) * 328 + ks * 32 + lg * 8];
#pragma unroll
    for (int ni = 0; ni < 4; ++ni)
      bf[ni] = w1v[(ks * 16 + (n0 >> 4) + ni) * 64 + lane];
#pragma unroll
    for (int mi = 0; mi < 4; ++mi)
#pragma unroll
      for (int ni = 0; ni < 4; ++ni)
        acc[mi][ni] = __builtin_amdgcn_mfma_f32_16x16x32_bf16(
            af[mi], bf[ni], acc[mi][ni], 0, 0, 0);
  }

  // ---- phase 3: bias + exact GELU, write h to LDS (bf16) ----
  float bias1[4];
#pragma unroll
  for (int ni = 0; ni < 4; ++ni) bias1[ni] = b1[n0 + ni * 16 + lr];
#pragma unroll
  for (int mi = 0; mi < 4; ++mi) {
#pragma unroll
    for (int ni = 0; ni < 4; ++ni) {
      int col = n0 + ni * 16 + lr;
#pragma unroll
      for (int q = 0; q < 4; ++q) {
        float h = acc[mi][ni][q] + bias1[ni];
        float g = 0.5f * h * (1.0f + erff(h * 0.70710678118654752f));
        hbuf[(mi * 16 + lg * 4 + q) * 264 + col] = f2bf(g);
      }
    }
  }
  __syncthreads();

  // ---- phase 4: GEMM2  [64 x 256] @ [256 x 64]; wave w does rows 16w..16w+15
  const int m0 = wv * 16;
  f32x4 acc2[4];
#pragma unroll
  for (int ni = 0; ni < 4; ++ni) acc2[ni] = 0;

  const short8v* w2v = (const short8v*)w2s;
  for (int ks = 0; ks < 8; ++ks) {
    short8v a2 = *(const short8v*)&hbuf[(m0 + lr) * 264 + ks * 32 + lg * 8];
#pragma unroll
    for (int ni = 0; ni < 4; ++ni) {
      short8v bfr = w2v[(ks * 4 + ni) * 64 + lane];
      acc2[ni] = __builtin_amdgcn_mfma_f32_16x16x32_bf16(a2, bfr, acc2[ni],
                                                         0, 0, 0);
    }
  }

  // ---- phase 5: epilogue  out = x + delta + b2  (fp32 residual) ----
#pragma unroll
  for (int ni = 0; ni < 4; ++ni) {
    int col = ni * 16 + lr;
    float bias = b2[col];
#pragma unroll
    for (int q = 0; q < 4; ++q) {
      int row = m0 + lg * 4 + q;          // pixel index within tile
      int py = row >> 3, px = row & 7;
      size_t idx =
          ((size_t)(batch * H_ + tileY + py) * W_ + (tileX + px)) * C_ + col;
      out[idx] = x[idx] + acc2[ni][q] + bias;
    }
  }
}

extern "C" void kernel_launch(void* const* d_in, const int* in_sizes, int n_in,
                              void* d_out, int out_size, void* d_ws,
                              size_t ws_size, hipStream_t stream) {
  const float* x  = (const float*)d_in[0];
  const float* cw = (const float*)d_in[1];
  const float* W1 = (const float*)d_in[2];
  const float* b1 = (const float*)d_in[3];
  const float* W2 = (const float*)d_in[4];
  const float* b2 = (const float*)d_in[5];
  float* out = (float*)d_out;

  ushort_t* w1s = (ushort_t*)d_ws;            // 81920 bf16 = 160 KB
  ushort_t* w2s = w1s + 81920;                // 16384 bf16 = 32 KB

  cvt_weights_kernel<<<384, 256, 0, stream>>>(W1, W2, w1s, w2s);

  dim3 grid(W_ / 8, H_ / 8, B_);              // 16 x 16 x 16 = 4096 blocks
  nca_fused_kernel<<<grid, 256, 0, stream>>>(x, cw, b1, b2, w1s, w2s, out);
}

// Round 2
// 231.179 us; speedup vs baseline: 1.6187x; 1.6187x over previous
//
#include <hip/hip_runtime.h>
#include <cstdint>

#define B_   16
#define H_   128
#define W_   128
#define C_   64
#define HID_ 256

typedef __attribute__((ext_vector_type(8))) short short8v;   // 8 bf16 (4 VGPRs)
typedef __attribute__((ext_vector_type(4))) float f32x4;

typedef unsigned short ushort_t;

__device__ __forceinline__ ushort_t f2bf(float f) {
  uint32_t u = __builtin_bit_cast(uint32_t, f);
  u += 0x7fff + ((u >> 16) & 1);          // round-to-nearest-even
  return (ushort_t)(u >> 16);
}

// XOR-swizzled LDS addressing (16B granules): row stride 320 ushorts (640 B,
// 160 dw == 0 mod 32 banks) would put all rows on the same banks; XOR-ing
// row&7 into the 8-ushort column-block index spreads 8 bank groups -> 2-way
// max on ds_read_b128 (free, m136).
__device__ __forceinline__ int fswz(int row, int col) {   // feat: 64x320
  return row * 320 + ((((col >> 3) ^ row) & 7) << 3) + (col & ~7 & 56) + (col & 7) - (col & 56);
}
// NOTE: simpler correct form used below; keep helpers minimal:
__device__ __forceinline__ int fs(int row, int col) {     // col in ushorts
  int cb = col >> 3;
  return row * 320 + ((cb ^ (row & 7)) << 3) + (col & 7);
}
__device__ __forceinline__ int hs(int row, int col) {     // hbuf: 64x256
  int cb = col >> 3;
  return row * 256 + ((cb ^ (row & 7)) << 3) + (col & 7);
}

// ---------------------------------------------------------------------------
// Phase 0: convert W1 [320x256] f32 and W2 [256x64] f32 into bf16 fragments
// pre-swizzled for mfma_f32_16x16x32_bf16 B-operand:
//   lane l of a fragment needs B[k0 + (l>>4)*8 + j][n0 + (l&15)], j=0..7
// w1s index: ((ks*16 + n16)*64 + lane)*8 + j   (ks=0..9, n16=0..15)
// w2s index: ((ks*4  + n16)*64 + lane)*8 + j   (ks=0..7, n16=0..3)
// ---------------------------------------------------------------------------
__global__ void cvt_weights_kernel(const float* __restrict__ W1,
                                   const float* __restrict__ W2,
                                   ushort_t* __restrict__ w1s,
                                   ushort_t* __restrict__ w2s) {
  int t = blockIdx.x * 256 + threadIdx.x;
  if (t < 81920) {
    int j = t & 7, lane = (t >> 3) & 63, n16 = (t >> 9) & 15, ks = t >> 13;
    int k = ks * 32 + (lane >> 4) * 8 + j;
    int n = n16 * 16 + (lane & 15);
    w1s[t] = f2bf(W1[k * 256 + n]);
  } else if (t < 81920 + 16384) {
    int t2 = t - 81920;
    int j = t2 & 7, lane = (t2 >> 3) & 63, n16 = (t2 >> 9) & 3, ks = t2 >> 11;
    int k = ks * 32 + (lane >> 4) * 8 + j;
    int n = n16 * 16 + (lane & 15);
    w2s[t2] = f2bf(W2[k * 64 + n]);
  }
}

// ---------------------------------------------------------------------------
// Depthwise dilated conv phase. BOUND=false for interior tiles (branch-free,
// compile-time tap offsets). cw weights hoisted out of the item loop.
// ---------------------------------------------------------------------------
template <bool BOUND>
__device__ __forceinline__ void conv_phase(const float* __restrict__ xb,
                                           const float* __restrict__ cw,
                                           ushort_t* __restrict__ feat,
                                           int tid, int tileX, int tileY) {
  const int quad  = tid & 15;
  const int prow0 = tid >> 4;
#pragma unroll
  for (int dd = 0; dd < 4; ++dd) {
    const int dil = 1 << dd;
    float4 wv[9];
#pragma unroll
    for (int t = 0; t < 9; ++t)
      wv[t] = *(const float4*)&cw[(dd * 9 + t) * C_ + quad * 4];
#pragma unroll
    for (int i = 0; i < 4; ++i) {
      const int p  = i * 16 + prow0;
      const int py = p >> 3, px = p & 7;
      const int y0 = tileY + py, x0 = tileX + px;
      float a0 = 0.f, a1 = 0.f, a2 = 0.f, a3 = 0.f;
#pragma unroll
      for (int ky = 0; ky < 3; ++ky) {
        const int yy = y0 + (ky - 1) * dil;
        if (BOUND && (unsigned)yy >= (unsigned)H_) continue;
#pragma unroll
        for (int kx = 0; kx < 3; ++kx) {
          const int xx = x0 + (kx - 1) * dil;
          if (BOUND && (unsigned)xx >= (unsigned)W_) continue;
          const float4 xv = *(const float4*)&xb[(yy * W_ + xx) * C_ + quad * 4];
          const float4 w  = wv[ky * 3 + kx];
          a0 = fmaf(xv.x, w.x, a0);
          a1 = fmaf(xv.y, w.y, a1);
          a2 = fmaf(xv.z, w.z, a2);
          a3 = fmaf(xv.w, w.w, a3);
        }
      }
      ushort4 pk;
      pk.x = f2bf(a0); pk.y = f2bf(a1); pk.z = f2bf(a2); pk.w = f2bf(a3);
      *(ushort4*)&feat[fs(p, 64 + dd * 64 + quad * 4)] = pk;
    }
  }
}

// ---------------------------------------------------------------------------
// Fused NCA kernel: one block = 8x8 pixel tile, 256 threads, 40 KB LDS
// (feat[64][320] bf16, aliased by hbuf[64][256] bf16 after GEMM1).
// ---------------------------------------------------------------------------
__global__ __launch_bounds__(256, 4)
void nca_fused_kernel(const float* __restrict__ x,
                      const float* __restrict__ cw,
                      const float* __restrict__ b1,
                      const float* __restrict__ b2,
                      const ushort_t* __restrict__ w1s,
                      const ushort_t* __restrict__ w2s,
                      float* __restrict__ out) {
  __shared__ __align__(16) ushort_t smem[64 * 320];   // 40960 B -> 4 blocks/CU

  const int tid   = threadIdx.x;
  const int tileX = blockIdx.x * 8;
  const int tileY = blockIdx.y * 8;
  const int batch = blockIdx.z;
  const float* xb = x + (size_t)batch * (H_ * W_ * C_);

  // ---- phase 1a: copy x tile into feat[:, 0:64] as bf16 ----
  {
    const int quad = tid & 15;
#pragma unroll
    for (int i = 0; i < 4; ++i) {
      const int p  = i * 16 + (tid >> 4);
      const int py = p >> 3, px = p & 7;
      const float4 v =
          *(const float4*)&xb[((tileY + py) * W_ + (tileX + px)) * C_ + quad * 4];
      ushort4 pk;
      pk.x = f2bf(v.x); pk.y = f2bf(v.y); pk.z = f2bf(v.z); pk.w = f2bf(v.w);
      *(ushort4*)&smem[fs(p, quad * 4)] = pk;
    }
  }

  // ---- phase 1b: 4 dilated depthwise convs ----
  const bool interior = (tileX >= 8) && (tileX <= W_ - 16) &&
                        (tileY >= 8) && (tileY <= H_ - 16);
  if (interior)
    conv_phase<false>(xb, cw, smem, tid, tileX, tileY);
  else
    conv_phase<true>(xb, cw, smem, tid, tileX, tileY);
  __syncthreads();

  // ---- phase 2: GEMM1  [64 x 320] @ [320 x 256] ----
  const int lane = tid & 63;
  const int wv   = tid >> 6;       // wave 0..3
  const int lr   = lane & 15;
  const int lg   = lane >> 4;
  const int n0   = wv * 64;

  f32x4 acc[4][4];
#pragma unroll
  for (int mi = 0; mi < 4; ++mi)
#pragma unroll
    for (int ni = 0; ni < 4; ++ni) acc[mi][ni] = 0;

  const short8v* w1v = (const short8v*)w1s;
  for (int ks = 0; ks < 10; ++ks) {
    short8v af[4], bf[4];
#pragma unroll
    for (int mi = 0; mi < 4; ++mi)
      af[mi] = *(const short8v*)&smem[fs(mi * 16 + lr, ks * 32 + lg * 8)];
#pragma unroll
    for (int ni = 0; ni < 4; ++ni)
      bf[ni] = w1v[(ks * 16 + (n0 >> 4) + ni) * 64 + lane];
#pragma unroll
    for (int mi = 0; mi < 4; ++mi)
#pragma unroll
      for (int ni = 0; ni < 4; ++ni)
        acc[mi][ni] = __builtin_amdgcn_mfma_f32_16x16x32_bf16(
            af[mi], bf[ni], acc[mi][ni], 0, 0, 0);
  }

  float bias1[4];
#pragma unroll
  for (int ni = 0; ni < 4; ++ni) bias1[ni] = b1[n0 + ni * 16 + lr];

  __syncthreads();   // feat's last read is done chip... block-wide; safe to alias

  // ---- phase 3: bias + exact GELU -> hbuf (aliases smem) ----
#pragma unroll
  for (int mi = 0; mi < 4; ++mi) {
#pragma unroll
    for (int ni = 0; ni < 4; ++ni) {
      const int col = n0 + ni * 16 + lr;
#pragma unroll
      for (int q = 0; q < 4; ++q) {
        float h = acc[mi][ni][q] + bias1[ni];
        float g = 0.5f * h * (1.0f + erff(h * 0.70710678118654752f));
        smem[hs(mi * 16 + lg * 4 + q, col)] = f2bf(g);
      }
    }
  }
  __syncthreads();

  // ---- phase 4: GEMM2  [64 x 256] @ [256 x 64]; wave w does rows 16w..16w+15
  const int m0 = wv * 16;
  f32x4 acc2[4];
#pragma unroll
  for (int ni = 0; ni < 4; ++ni) acc2[ni] = 0;

  const short8v* w2v = (const short8v*)w2s;
  for (int ks = 0; ks < 8; ++ks) {
    short8v a2 = *(const short8v*)&smem[hs(m0 + lr, ks * 32 + lg * 8)];
#pragma unroll
    for (int ni = 0; ni < 4; ++ni) {
      short8v bfr = w2v[(ks * 4 + ni) * 64 + lane];
      acc2[ni] = __builtin_amdgcn_mfma_f32_16x16x32_bf16(a2, bfr, acc2[ni],
                                                         0, 0, 0);
    }
  }

  // ---- phase 5: epilogue  out = x + delta + b2  (fp32 residual) ----
#pragma unroll
  for (int ni = 0; ni < 4; ++ni) {
    const int col  = ni * 16 + lr;
    const float bias = b2[col];
#pragma unroll
    for (int q = 0; q < 4; ++q) {
      const int row = m0 + lg * 4 + q;          // pixel index within tile
      const int py = row >> 3, px = row & 7;
      const size_t idx =
          ((size_t)(batch * H_ + tileY + py) * W_ + (tileX + px)) * C_ + col;
      out[idx] = x[idx] + acc2[ni][q] + bias;
    }
  }
}

extern "C" void kernel_launch(void* const* d_in, const int* in_sizes, int n_in,
                              void* d_out, int out_size, void* d_ws,
                              size_t ws_size, hipStream_t stream) {
  const float* x  = (const float*)d_in[0];
  const float* cw = (const float*)d_in[1];
  const float* W1 = (const float*)d_in[2];
  const float* b1 = (const float*)d_in[3];
  const float* W2 = (const float*)d_in[4];
  const float* b2 = (const float*)d_in[5];
  float* out = (float*)d_out;

  ushort_t* w1s = (ushort_t*)d_ws;            // 81920 bf16 = 160 KB
  ushort_t* w2s = w1s + 81920;                // 16384 bf16 = 32 KB

  cvt_weights_kernel<<<384, 256, 0, stream>>>(W1, W2, w1s, w2s);

  dim3 grid(W_ / 8, H_ / 8, B_);              // 16 x 16 x 16 = 4096 blocks
  nca_fused_kernel<<<grid, 256, 0, stream>>>(x, cw, b1, b2, w1s, w2s, out);
}